// Round 2
// baseline (333.840 us; speedup 1.0000x reference)
//
#include <hip/hip_runtime.h>

// CondInst dynamic mask head, fused: per-instance MLP (10->8->8->1, x2 heads)
// + aligned_bilinear x2 upsample + sigmoid.
// Shapes (from reference setup): mask_feats (2,8,200,200) f32,
// params (128,169) f32 x2, locs (128,2) f32, im_inds/fpn_levels int32,
// stride scalar int (=8). Output: 2 x (128,1,400,400) f32 concat flat.

#define BLOCK 256
#define Hh 200
#define Ww 200
#define CINCH 8
#define NP 169
#define TH 25      // output rows per tile
#define MAXR 14    // max head rows needed per tile (factor=2)
#define OW 400
#define OH 400

__global__ __launch_bounds__(BLOCK) void dmh_fused(
    const float* __restrict__ mask_feats,
    const float* __restrict__ mparams,
    const float* __restrict__ bparams,
    const float* __restrict__ ilocs,
    const int*   __restrict__ im_inds,
    const int*   __restrict__ fpn_levels,
    const int*   __restrict__ stride_p,
    float* __restrict__ out,
    int n_inst)
{
    // params repacked: per head 192 floats:
    //   w0 rows (8 x 10) at stride 12 -> [0,96)   (16B-aligned rows)
    //   w1 rows (8 x 8)               -> [96,160)
    //   w2 (8)                        -> [160,168)
    //   b0 (8) -> [168,176), b1 (8) -> [176,184), b2 -> [184]
    __shared__ __align__(16) float s_par[2 * 192];
    __shared__ __align__(16) float s_m[2][MAXR][Ww];

    const int tid  = threadIdx.x;
    const int tile = blockIdx.x;   // 0..15
    const int inst = blockIdx.y;

    for (int j = tid; j < 2 * NP; j += BLOCK) {
        const int head = (j < NP) ? 0 : 1;
        const int k = j - head * NP;
        const float v = head ? bparams[inst * NP + k] : mparams[inst * NP + k];
        int dst;
        if      (k < 80)  dst = (k / 10) * 12 + (k % 10);
        else if (k < 144) dst = 96 + (k - 80);
        else if (k < 152) dst = 160 + (k - 144);
        else if (k < 160) dst = 168 + (k - 152);
        else if (k < 168) dst = 176 + (k - 160);
        else              dst = 184;
        s_par[head * 192 + dst] = v;
    }

    const int   s    = stride_p[0];       // 8
    const int   half = s >> 1;            // stride // 2
    const int   im   = im_inds[inst];
    const int   lvl  = fpn_levels[inst];
    const float inv_soi = 1.0f / (float)(64 << lvl);  // SOI = 64*2^lvl exactly
    const float ixl = ilocs[inst * 2 + 0];
    const float iyl = ilocs[inst * 2 + 1];

    const int i0 = tile * TH;
    const int r_begin = ((i0 > 0) ? (i0 - 1) : 0) >> 1;
    int r_end = ((i0 + TH - 2) >> 1) + 1;
    if (r_end > Hh - 1) r_end = Hh - 1;
    const int nrows = r_end - r_begin + 1;   // <= 14

    __syncthreads();

    // ---------- Phase A: head MLP at 200-res into LDS ----------
    const int npx = nrows * Ww;                 // multiple of 4
    const float* fbase = mask_feats + (size_t)im * CINCH * Hh * Ww;

    for (int g = tid * 4; g < npx; g += BLOCK * 4) {
        const int lr = g / Ww;
        const int c  = g - lr * Ww;             // multiple of 4
        const int r  = r_begin + lr;

        float xv[10][4];
        {
            const float ry = (iyl - (float)(r * s + half)) * inv_soi;
            #pragma unroll
            for (int k = 0; k < 4; k++) {
                xv[0][k] = (ixl - (float)((c + k) * s + half)) * inv_soi;
                xv[1][k] = ry;
            }
            const float* fp = fbase + r * Ww + c;
            #pragma unroll
            for (int ch = 0; ch < 8; ch++) {
                const float4 f = *(const float4*)(fp + ch * (Hh * Ww));
                xv[2 + ch][0] = f.x; xv[2 + ch][1] = f.y;
                xv[2 + ch][2] = f.z; xv[2 + ch][3] = f.w;
            }
        }

        #pragma unroll
        for (int head = 0; head < 2; head++) {
            const float* P = s_par + head * 192;
            float h1[8][4];
            #pragma unroll
            for (int o = 0; o < 8; o++) {
                const float4 wa = *(const float4*)(P + o * 12);
                const float4 wb = *(const float4*)(P + o * 12 + 4);
                const float2 wc = *(const float2*)(P + o * 12 + 8);
                const float  b  = P[168 + o];
                #pragma unroll
                for (int k = 0; k < 4; k++) {
                    float a = b;
                    a += wa.x * xv[0][k] + wa.y * xv[1][k] + wa.z * xv[2][k] + wa.w * xv[3][k];
                    a += wb.x * xv[4][k] + wb.y * xv[5][k] + wb.z * xv[6][k] + wb.w * xv[7][k];
                    a += wc.x * xv[8][k] + wc.y * xv[9][k];
                    h1[o][k] = fmaxf(a, 0.0f);
                }
            }
            float h2[8][4];
            #pragma unroll
            for (int o = 0; o < 8; o++) {
                const float4 wa = *(const float4*)(P + 96 + o * 8);
                const float4 wb = *(const float4*)(P + 96 + o * 8 + 4);
                const float  b  = P[176 + o];
                #pragma unroll
                for (int k = 0; k < 4; k++) {
                    float a = b;
                    a += wa.x * h1[0][k] + wa.y * h1[1][k] + wa.z * h1[2][k] + wa.w * h1[3][k];
                    a += wb.x * h1[4][k] + wb.y * h1[5][k] + wb.z * h1[6][k] + wb.w * h1[7][k];
                    h2[o][k] = fmaxf(a, 0.0f);
                }
            }
            const float4 wa = *(const float4*)(P + 160);
            const float4 wb = *(const float4*)(P + 164);
            const float  b  = P[184];
            float4 res;
            float tmp[4];
            #pragma unroll
            for (int k = 0; k < 4; k++) {
                float a = b;
                a += wa.x * h2[0][k] + wa.y * h2[1][k] + wa.z * h2[2][k] + wa.w * h2[3][k];
                a += wb.x * h2[4][k] + wb.y * h2[5][k] + wb.z * h2[6][k] + wb.w * h2[7][k];
                tmp[k] = a;
            }
            res.x = tmp[0]; res.y = tmp[1]; res.z = tmp[2]; res.w = tmp[3];
            *(float4*)(&s_m[head][lr][c]) = res;
        }
    }

    __syncthreads();

    // ---------- Phase B: aligned_bilinear x2 + sigmoid ----------
    float* out0 = out + (size_t)inst * (OH * OW) + (size_t)i0 * OW;
    float* out1 = out0 + (size_t)n_inst * (OH * OW);

    for (int p = tid; p < TH * OW; p += BLOCK) {
        const int il = p / OW;
        const int j  = p - il * OW;
        const int i  = i0 + il;
        const int ip = (i > 0) ? (i - 1) : 0;
        const int jp = (j > 0) ? (j - 1) : 0;
        const int y0 = ip >> 1;
        const int x0 = jp >> 1;
        const float wy = (ip & 1) ? 0.5f : 0.0f;
        const float wx = (jp & 1) ? 0.5f : 0.0f;
        const int lr0 = y0 - r_begin;
        const int r1c = (y0 + 1 <= Hh - 1) ? (y0 + 1) : (Hh - 1);
        const int lr1 = r1c - r_begin;
        const int c1  = (x0 + 1 <= Ww - 1) ? (x0 + 1) : (Ww - 1);

        #pragma unroll
        for (int head = 0; head < 2; head++) {
            const float v00 = s_m[head][lr0][x0];
            const float v01 = s_m[head][lr0][c1];
            const float v10 = s_m[head][lr1][x0];
            const float v11 = s_m[head][lr1][c1];
            const float top = v00 + (v01 - v00) * wx;
            const float bot = v10 + (v11 - v10) * wx;
            const float v   = top + (bot - top) * wy;
            const float sg  = 1.0f / (1.0f + __expf(-v));
            (head ? out1 : out0)[il * OW + j] = sg;
        }
    }
}

extern "C" void kernel_launch(void* const* d_in, const int* in_sizes, int n_in,
                              void* d_out, int out_size, void* d_ws, size_t ws_size,
                              hipStream_t stream) {
    const float* mask_feats = (const float*)d_in[0];
    const float* mparams    = (const float*)d_in[1];
    const float* bparams    = (const float*)d_in[2];
    const float* ilocs      = (const float*)d_in[3];
    const int*   im_inds    = (const int*)d_in[4];
    const int*   fpn_levels = (const int*)d_in[5];
    const int*   stride_p   = (const int*)d_in[6];
    float* out = (float*)d_out;

    const int n_inst = in_sizes[1] / NP;      // 128
    dim3 grid(OH / TH, n_inst);               // (16, 128)
    dim3 block(BLOCK);
    hipLaunchKernelGGL(dmh_fused, grid, block, 0, stream,
                       mask_feats, mparams, bparams, ilocs,
                       im_inds, fpn_levels, stride_p, out, n_inst);
}

// Round 4
// 101.848 us; speedup vs baseline: 3.2778x; 3.2778x over previous
//
#include <hip/hip_runtime.h>

// CondInst dynamic mask head, fused: per-instance MLP (10->8->8->1, x2 heads)
// + aligned_bilinear x2 upsample + sigmoid.
// mask_feats (2,8,200,200) f32, params (128,169) f32 x2, locs (128,2) f32,
// im_inds/fpn_levels int32, stride scalar int (=8).
// Output: 2 x (128,1,400,400) f32 concat flat.

#define BLOCK 256
#define Hh 200
#define Ww 200
#define CINCH 8
#define NP 169
#define TH 25      // output rows per tile
#define MAXR 14    // max head rows needed per tile (factor=2)
#define OW 400
#define OH 400

typedef float f32x4 __attribute__((ext_vector_type(4)));

__global__ __launch_bounds__(BLOCK, 4) void dmh_fused(
    const float* __restrict__ mask_feats,
    const float* __restrict__ mparams,
    const float* __restrict__ bparams,
    const float* __restrict__ ilocs,
    const int*   __restrict__ im_inds,
    const int*   __restrict__ fpn_levels,
    const int*   __restrict__ stride_p,
    float* __restrict__ out,
    int n_inst)
{
    // params repacked per head into 192 floats (16B-aligned rows):
    //   w0 rows (8 x 10) stride 12 -> [0,96)
    //   w1 rows (8 x 8)            -> [96,160)
    //   w2 (8)                     -> [160,168)
    //   b0 -> [168,176), b1 -> [176,184), b2 -> [184]
    __shared__ __align__(16) float s_par[2 * 192];
    __shared__ __align__(16) float s_m[2][MAXR][Ww];

    const int tid  = threadIdx.x;
    const int tile = blockIdx.x;   // 0..15
    const int inst = blockIdx.y;

    for (int j = tid; j < 2 * NP; j += BLOCK) {
        const int head = (j < NP) ? 0 : 1;
        const int k = j - head * NP;
        const float v = head ? bparams[inst * NP + k] : mparams[inst * NP + k];
        int dst;
        if      (k < 80)  dst = (k / 10) * 12 + (k % 10);
        else if (k < 144) dst = 96 + (k - 80);
        else if (k < 152) dst = 160 + (k - 144);
        else if (k < 160) dst = 168 + (k - 152);
        else if (k < 168) dst = 176 + (k - 160);
        else              dst = 184;
        s_par[head * 192 + dst] = v;
    }

    const int   s    = stride_p[0];       // 8
    const int   half = s >> 1;
    const int   im   = im_inds[inst];
    const int   lvl  = fpn_levels[inst];
    const float inv_soi = 1.0f / (float)(64 << lvl);  // SOI = 64*2^lvl exactly
    const float ixl = ilocs[inst * 2 + 0];
    const float iyl = ilocs[inst * 2 + 1];

    const int i0 = tile * TH;
    const int r_begin = ((i0 > 0) ? (i0 - 1) : 0) >> 1;
    int r_end = ((i0 + TH - 2) >> 1) + 1;
    if (r_end > Hh - 1) r_end = Hh - 1;
    const int nrows = r_end - r_begin + 1;   // <= 14

    __syncthreads();

    // ---------- Phase A: head MLP at 200-res into LDS ----------
    const int npx = nrows * Ww;                 // multiple of 4
    const float* fbase = mask_feats + (size_t)im * CINCH * Hh * Ww;

    for (int g = tid * 4; g < npx; g += BLOCK * 4) {
        // prevent hoisting of LDS weight loads across iterations (VGPR blowup)
        asm volatile("" ::: "memory");

        const int lr = g / Ww;
        const int c  = g - lr * Ww;             // multiple of 4
        const int r  = r_begin + lr;

        float xv[10][4];
        {
            const float ry = (iyl - (float)(r * s + half)) * inv_soi;
            #pragma unroll
            for (int k = 0; k < 4; k++) {
                xv[0][k] = (ixl - (float)((c + k) * s + half)) * inv_soi;
                xv[1][k] = ry;
            }
            const float* fp = fbase + r * Ww + c;
            #pragma unroll
            for (int ch = 0; ch < 8; ch++) {
                const f32x4 f = *(const f32x4*)(fp + ch * (Hh * Ww));
                xv[2 + ch][0] = f.x; xv[2 + ch][1] = f.y;
                xv[2 + ch][2] = f.z; xv[2 + ch][3] = f.w;
            }
        }

        #pragma unroll 1
        for (int head = 0; head < 2; head++) {
            const float* P = s_par + head * 192;
            float h1[8][4];
            #pragma unroll
            for (int o = 0; o < 8; o++) {
                const f32x4 wa = *(const f32x4*)(P + o * 12);
                const f32x4 wb = *(const f32x4*)(P + o * 12 + 4);
                const float wc0 = P[o * 12 + 8];
                const float wc1 = P[o * 12 + 9];
                const float b   = P[168 + o];
                #pragma unroll
                for (int k = 0; k < 4; k++) {
                    float a = b;
                    a += wa.x * xv[0][k] + wa.y * xv[1][k] + wa.z * xv[2][k] + wa.w * xv[3][k];
                    a += wb.x * xv[4][k] + wb.y * xv[5][k] + wb.z * xv[6][k] + wb.w * xv[7][k];
                    a += wc0 * xv[8][k] + wc1 * xv[9][k];
                    h1[o][k] = fmaxf(a, 0.0f);
                }
            }
            float h2[8][4];
            #pragma unroll
            for (int o = 0; o < 8; o++) {
                const f32x4 wa = *(const f32x4*)(P + 96 + o * 8);
                const f32x4 wb = *(const f32x4*)(P + 96 + o * 8 + 4);
                const float b  = P[176 + o];
                #pragma unroll
                for (int k = 0; k < 4; k++) {
                    float a = b;
                    a += wa.x * h1[0][k] + wa.y * h1[1][k] + wa.z * h1[2][k] + wa.w * h1[3][k];
                    a += wb.x * h1[4][k] + wb.y * h1[5][k] + wb.z * h1[6][k] + wb.w * h1[7][k];
                    h2[o][k] = fmaxf(a, 0.0f);
                }
            }
            const f32x4 wa = *(const f32x4*)(P + 160);
            const f32x4 wb = *(const f32x4*)(P + 164);
            const float b  = P[184];
            f32x4 res;
            #pragma unroll
            for (int k = 0; k < 4; k++) {
                float a = b;
                a += wa.x * h2[0][k] + wa.y * h2[1][k] + wa.z * h2[2][k] + wa.w * h2[3][k];
                a += wb.x * h2[4][k] + wb.y * h2[5][k] + wb.z * h2[6][k] + wb.w * h2[7][k];
                res[k] = a;
            }
            *(f32x4*)(&s_m[head][lr][c]) = res;
        }
    }

    __syncthreads();

    // ---------- Phase B: aligned_bilinear x2 + sigmoid, f32x4 nt stores ----------
    float* out0 = out + (size_t)inst * (OH * OW) + (size_t)i0 * OW;
    float* out1 = out0 + (size_t)n_inst * (OH * OW);

    const int nquad = TH * OW / 4;   // 2500
    for (int q = tid; q < nquad; q += BLOCK) {
        const int il = q / (OW / 4);
        const int jq = (q - il * (OW / 4)) * 4;
        const int i  = i0 + il;
        const int ip = (i > 0) ? (i - 1) : 0;
        const int y0 = ip >> 1;
        const float wy = (ip & 1) ? 0.5f : 0.0f;
        const int lr0 = y0 - r_begin;
        const int r1c = (y0 + 1 <= Hh - 1) ? (y0 + 1) : (Hh - 1);
        const int lr1 = r1c - r_begin;

        f32x4 r0, r1;
        #pragma unroll
        for (int k = 0; k < 4; k++) {
            const int j  = jq + k;
            const int jp = (j > 0) ? (j - 1) : 0;
            const int x0 = jp >> 1;
            const float wx = (jp & 1) ? 0.5f : 0.0f;
            const int c1 = (x0 + 1 <= Ww - 1) ? (x0 + 1) : (Ww - 1);

            #pragma unroll
            for (int head = 0; head < 2; head++) {
                const float v00 = s_m[head][lr0][x0];
                const float v01 = s_m[head][lr0][c1];
                const float v10 = s_m[head][lr1][x0];
                const float v11 = s_m[head][lr1][c1];
                const float top = v00 + (v01 - v00) * wx;
                const float bot = v10 + (v11 - v10) * wx;
                const float v   = top + (bot - top) * wy;
                const float sg  = 1.0f / (1.0f + __expf(-v));
                if (head) r1[k] = sg; else r0[k] = sg;
            }
        }
        __builtin_nontemporal_store(r0, (f32x4*)(out0 + il * OW + jq));
        __builtin_nontemporal_store(r1, (f32x4*)(out1 + il * OW + jq));
    }
}

extern "C" void kernel_launch(void* const* d_in, const int* in_sizes, int n_in,
                              void* d_out, int out_size, void* d_ws, size_t ws_size,
                              hipStream_t stream) {
    const float* mask_feats = (const float*)d_in[0];
    const float* mparams    = (const float*)d_in[1];
    const float* bparams    = (const float*)d_in[2];
    const float* ilocs      = (const float*)d_in[3];
    const int*   im_inds    = (const int*)d_in[4];
    const int*   fpn_levels = (const int*)d_in[5];
    const int*   stride_p   = (const int*)d_in[6];
    float* out = (float*)d_out;

    const int n_inst = in_sizes[1] / NP;      // 128
    dim3 grid(OH / TH, n_inst);               // (16, 128)
    dim3 block(BLOCK);
    hipLaunchKernelGGL(dmh_fused, grid, block, 0, stream,
                       mask_feats, mparams, bparams, ilocs,
                       im_inds, fpn_levels, stride_p, out, n_inst);
}

// Round 5
// 71.953 us; speedup vs baseline: 4.6397x; 1.4155x over previous
//
#include <hip/hip_runtime.h>

// CondInst dynamic mask head, fused: per-instance MLP (10->8->8->1, x2 heads)
// + aligned_bilinear x2 upsample + sigmoid.
// mask_feats (2,8,200,200) f32, params (128,169) f32 x2, locs (128,2) f32,
// im_inds/fpn_levels int32, stride scalar int (=8).
// Output: 2 x (128,1,400,400) f32 concat flat.

#define BLOCK 256
#define Hh 200
#define Ww 200
#define CINCH 8
#define NP 169
#define TH 25      // output rows per tile
#define MAXR 14    // max head rows needed per tile (factor=2)
#define OW 400
#define OH 400

typedef float f32x4 __attribute__((ext_vector_type(4)));
typedef float f32x2 __attribute__((ext_vector_type(2)));

__device__ __forceinline__ f32x2 splat2(float v) { f32x2 r; r.x = v; r.y = v; return r; }
__device__ __forceinline__ f32x2 pkfma(f32x2 a, f32x2 b, f32x2 c) {
    return __builtin_elementwise_fma(a, b, c);
}

__global__ __launch_bounds__(BLOCK, 3) void dmh_fused(
    const float* __restrict__ mask_feats,
    const float* __restrict__ mparams,
    const float* __restrict__ bparams,
    const float* __restrict__ ilocs,
    const int*   __restrict__ im_inds,
    const int*   __restrict__ fpn_levels,
    const int*   __restrict__ stride_p,
    float* __restrict__ out,
    int n_inst)
{
    // params repacked per head into 192 floats (16B-aligned rows):
    //   w0 rows (8 x 10) stride 12 -> [0,96)
    //   w1 rows (8 x 8)            -> [96,160)
    //   w2 (8)                     -> [160,168)
    //   b0 -> [168,176), b1 -> [176,184), b2 -> [184]
    __shared__ __align__(16) float s_par[2 * 192];
    __shared__ __align__(16) float s_m[2][MAXR][Ww];

    const int tid  = threadIdx.x;
    const int tile = blockIdx.x;   // 0..15
    const int inst = blockIdx.y;

    for (int j = tid; j < 2 * NP; j += BLOCK) {
        const int head = (j < NP) ? 0 : 1;
        const int k = j - head * NP;
        const float v = head ? bparams[inst * NP + k] : mparams[inst * NP + k];
        int dst;
        if      (k < 80)  dst = (k / 10) * 12 + (k % 10);
        else if (k < 144) dst = 96 + (k - 80);
        else if (k < 152) dst = 160 + (k - 144);
        else if (k < 160) dst = 168 + (k - 152);
        else if (k < 168) dst = 176 + (k - 160);
        else              dst = 184;
        s_par[head * 192 + dst] = v;
    }

    const int   s    = stride_p[0];       // 8
    const int   half = s >> 1;
    const int   im   = im_inds[inst];
    const int   lvl  = fpn_levels[inst];
    const float inv_soi = 1.0f / (float)(64 << lvl);  // SOI = 64*2^lvl exactly
    const float ixl = ilocs[inst * 2 + 0];
    const float iyl = ilocs[inst * 2 + 1];

    const int i0 = tile * TH;
    const int r_begin = ((i0 > 0) ? (i0 - 1) : 0) >> 1;
    int r_end = ((i0 + TH - 2) >> 1) + 1;
    if (r_end > Hh - 1) r_end = Hh - 1;
    const int nrows = r_end - r_begin + 1;   // <= 14

    __syncthreads();

    // ---------- Phase A: head MLP at 200-res into LDS (pk-f32, 4 px/thread) ----------
    const int npx = nrows * Ww;                 // multiple of 4
    const float* fbase = mask_feats + (size_t)im * CINCH * Hh * Ww;

    for (int g = tid * 4; g < npx; g += BLOCK * 4) {
        // prevent hoisting of LDS weight loads across iterations (VGPR blowup)
        asm volatile("" ::: "memory");

        const int lr = g / Ww;
        const int c  = g - lr * Ww;             // multiple of 4
        const int r  = r_begin + lr;

        // xa = px {0,1}, xb = px {2,3} for the 10 input channels
        f32x2 xa[10], xb[10];
        {
            const float ry   = (iyl - (float)(r * s + half)) * inv_soi;
            const float step = -(float)s * inv_soi;
            const float cx0  = (ixl - (float)(c * s + half)) * inv_soi;
            xa[0].x = cx0;            xa[0].y = cx0 + step;
            xb[0].x = cx0 + 2*step;   xb[0].y = cx0 + 3*step;
            xa[1] = splat2(ry);       xb[1] = xa[1];
            const float* fp = fbase + r * Ww + c;
            #pragma unroll
            for (int ch = 0; ch < 8; ch++) {
                const f32x4 f = *(const f32x4*)(fp + ch * (Hh * Ww));
                xa[2 + ch].x = f.x; xa[2 + ch].y = f.y;
                xb[2 + ch].x = f.z; xb[2 + ch].y = f.w;
            }
        }

        #pragma unroll 1
        for (int head = 0; head < 2; head++) {
            const float* P = s_par + head * 192;
            const f32x2 zero = splat2(0.0f);

            f32x2 h1a[8], h1b[8];
            #pragma unroll
            for (int o = 0; o < 8; o++) {
                const f32x4 wa = *(const f32x4*)(P + o * 12);
                const f32x4 wb = *(const f32x4*)(P + o * 12 + 4);
                const float w8 = P[o * 12 + 8];
                const float w9 = P[o * 12 + 9];
                f32x2 aa = splat2(P[168 + o]);
                f32x2 ab = aa;
                aa = pkfma(splat2(wa.x), xa[0], aa); ab = pkfma(splat2(wa.x), xb[0], ab);
                aa = pkfma(splat2(wa.y), xa[1], aa); ab = pkfma(splat2(wa.y), xb[1], ab);
                aa = pkfma(splat2(wa.z), xa[2], aa); ab = pkfma(splat2(wa.z), xb[2], ab);
                aa = pkfma(splat2(wa.w), xa[3], aa); ab = pkfma(splat2(wa.w), xb[3], ab);
                aa = pkfma(splat2(wb.x), xa[4], aa); ab = pkfma(splat2(wb.x), xb[4], ab);
                aa = pkfma(splat2(wb.y), xa[5], aa); ab = pkfma(splat2(wb.y), xb[5], ab);
                aa = pkfma(splat2(wb.z), xa[6], aa); ab = pkfma(splat2(wb.z), xb[6], ab);
                aa = pkfma(splat2(wb.w), xa[7], aa); ab = pkfma(splat2(wb.w), xb[7], ab);
                aa = pkfma(splat2(w8),   xa[8], aa); ab = pkfma(splat2(w8),   xb[8], ab);
                aa = pkfma(splat2(w9),   xa[9], aa); ab = pkfma(splat2(w9),   xb[9], ab);
                h1a[o] = __builtin_elementwise_max(aa, zero);
                h1b[o] = __builtin_elementwise_max(ab, zero);
            }

            f32x2 h2a[8], h2b[8];
            #pragma unroll
            for (int o = 0; o < 8; o++) {
                const f32x4 wa = *(const f32x4*)(P + 96 + o * 8);
                const f32x4 wb = *(const f32x4*)(P + 96 + o * 8 + 4);
                f32x2 aa = splat2(P[176 + o]);
                f32x2 ab = aa;
                aa = pkfma(splat2(wa.x), h1a[0], aa); ab = pkfma(splat2(wa.x), h1b[0], ab);
                aa = pkfma(splat2(wa.y), h1a[1], aa); ab = pkfma(splat2(wa.y), h1b[1], ab);
                aa = pkfma(splat2(wa.z), h1a[2], aa); ab = pkfma(splat2(wa.z), h1b[2], ab);
                aa = pkfma(splat2(wa.w), h1a[3], aa); ab = pkfma(splat2(wa.w), h1b[3], ab);
                aa = pkfma(splat2(wb.x), h1a[4], aa); ab = pkfma(splat2(wb.x), h1b[4], ab);
                aa = pkfma(splat2(wb.y), h1a[5], aa); ab = pkfma(splat2(wb.y), h1b[5], ab);
                aa = pkfma(splat2(wb.z), h1a[6], aa); ab = pkfma(splat2(wb.z), h1b[6], ab);
                aa = pkfma(splat2(wb.w), h1a[7], aa); ab = pkfma(splat2(wb.w), h1b[7], ab);
                h2a[o] = __builtin_elementwise_max(aa, zero);
                h2b[o] = __builtin_elementwise_max(ab, zero);
            }

            const f32x4 wa = *(const f32x4*)(P + 160);
            const f32x4 wb = *(const f32x4*)(P + 164);
            f32x2 aa = splat2(P[184]);
            f32x2 ab = aa;
            aa = pkfma(splat2(wa.x), h2a[0], aa); ab = pkfma(splat2(wa.x), h2b[0], ab);
            aa = pkfma(splat2(wa.y), h2a[1], aa); ab = pkfma(splat2(wa.y), h2b[1], ab);
            aa = pkfma(splat2(wa.z), h2a[2], aa); ab = pkfma(splat2(wa.z), h2b[2], ab);
            aa = pkfma(splat2(wa.w), h2a[3], aa); ab = pkfma(splat2(wa.w), h2b[3], ab);
            aa = pkfma(splat2(wb.x), h2a[4], aa); ab = pkfma(splat2(wb.x), h2b[4], ab);
            aa = pkfma(splat2(wb.y), h2a[5], aa); ab = pkfma(splat2(wb.y), h2b[5], ab);
            aa = pkfma(splat2(wb.z), h2a[6], aa); ab = pkfma(splat2(wb.z), h2b[6], ab);
            aa = pkfma(splat2(wb.w), h2a[7], aa); ab = pkfma(splat2(wb.w), h2b[7], ab);

            f32x4 res;
            res.x = aa.x; res.y = aa.y; res.z = ab.x; res.w = ab.y;
            *(f32x4*)(&s_m[head][lr][c]) = res;
        }
    }

    __syncthreads();

    // ---------- Phase B: aligned_bilinear x2 + sigmoid ----------
    // Each task: one output row segment of 8 px from one aligned f32x4 per
    // source row (conflict-free ds_read_b128) + 1 guarded scalar left-neighbor.
    float* out0 = out + (size_t)inst * (OH * OW) + (size_t)i0 * OW;
    float* out1 = out0 + (size_t)n_inst * (OH * OW);

    const int NU = OW / 8;            // 50 groups per row
    const int ntask = TH * NU;        // 1250
    for (int t = tid; t < ntask; t += BLOCK) {
        const int row = t / NU;
        const int u   = t - row * NU;
        const int i   = i0 + row;
        const int ip  = (i > 0) ? (i - 1) : 0;
        const int y0  = ip >> 1;
        const float wy = (ip & 1) ? 0.5f : 0.0f;
        const int lr0 = y0 - r_begin;
        const int r1c = (y0 + 1 <= Hh - 1) ? (y0 + 1) : (Hh - 1);
        const int lr1 = r1c - r_begin;

        #pragma unroll
        for (int head = 0; head < 2; head++) {
            const f32x4 A0 = *(const f32x4*)(&s_m[head][lr0][4 * u]);
            const f32x4 A1 = *(const f32x4*)(&s_m[head][lr1][4 * u]);
            float p0 = 0.0f, p1 = 0.0f;
            if (u > 0) {
                p0 = s_m[head][lr0][4 * u - 1];
                p1 = s_m[head][lr1][4 * u - 1];
            }
            // y-interp first (wy in {0,0.5} exact)
            f32x4 B;
            B.x = A0.x + (A1.x - A0.x) * wy;
            B.y = A0.y + (A1.y - A0.y) * wy;
            B.z = A0.z + (A1.z - A0.z) * wy;
            B.w = A0.w + (A1.w - A0.w) * wy;
            const float PB = p0 + (p1 - p0) * wy;

            float o[8];
            o[0] = (u > 0) ? 0.5f * (PB + B.x) : B.x;
            o[1] = B.x;
            o[2] = 0.5f * (B.x + B.y);
            o[3] = B.y;
            o[4] = 0.5f * (B.y + B.z);
            o[5] = B.z;
            o[6] = 0.5f * (B.z + B.w);
            o[7] = B.w;

            f32x4 lo, hi;
            #pragma unroll
            for (int k = 0; k < 4; k++) lo[k] = 1.0f / (1.0f + __expf(-o[k]));
            #pragma unroll
            for (int k = 0; k < 4; k++) hi[k] = 1.0f / (1.0f + __expf(-o[4 + k]));

            float* dst = (head ? out1 : out0) + row * OW + 8 * u;
            __builtin_nontemporal_store(lo, (f32x4*)dst);
            __builtin_nontemporal_store(hi, (f32x4*)(dst + 4));
        }
    }
}

extern "C" void kernel_launch(void* const* d_in, const int* in_sizes, int n_in,
                              void* d_out, int out_size, void* d_ws, size_t ws_size,
                              hipStream_t stream) {
    const float* mask_feats = (const float*)d_in[0];
    const float* mparams    = (const float*)d_in[1];
    const float* bparams    = (const float*)d_in[2];
    const float* ilocs      = (const float*)d_in[3];
    const int*   im_inds    = (const int*)d_in[4];
    const int*   fpn_levels = (const int*)d_in[5];
    const int*   stride_p   = (const int*)d_in[6];
    float* out = (float*)d_out;

    const int n_inst = in_sizes[1] / NP;      // 128
    dim3 grid(OH / TH, n_inst);               // (16, 128)
    dim3 block(BLOCK);
    hipLaunchKernelGGL(dmh_fused, grid, block, 0, stream,
                       mask_feats, mparams, bparams, ilocs,
                       im_inds, fpn_levels, stride_p, out, n_inst);
}